// Round 6
// baseline (817.760 us; speedup 1.0000x reference)
//
#include <hip/hip_runtime.h>

// 2-layer LSTM (H=64) encode(128) + AR(60), B=4096, persistent per-block.
// ROUND-6 = ROUND-4 STRUCTURE + TWO-SIDED REGISTER PARTITION.
// 256 blocks x 1024 threads (16 waves), M_BLK=16 rows as TWO independent
// 8-row chains; wave%4 -> SIMD gives 4 independent streams per SIMD
// {c0L1, c0L0, c1L1, c1L0}. At the 128-reg/wave budget the compiler
// splits the unified file 64 arch + 64 acc:
//   round-4: weights in arch -> arch overflow -> scratch spills (66MB).
//   round-5: weights pinned acc, but MFMA accumulators ALSO went acc ->
//            acc overflow -> AGPR spills (double-cost) -> worse (120MB).
// Fix here: pin BOTH sides of the partition.
//   - PIN_AGPR(Bw[kt][tau]): the 16 weight fragments = exactly 64 acc.
//   - PIN_VGPR(Cpre[tau]) at every accumulator init + ONE shared Cpre[4]
//     array for prologue/encode/AR (no second C array exists) -> all
//     MFMA C/D in arch VGPRs (vgpr-form v_mfma; B reads AGPR directly).
//   - Head weights (Bfc) in a 2KB LDS table; arch demand ~60 <= 64.
// Per-row arithmetic identical to the round-0..5 passing kernels.

#define T_ENC 128
#define D_IN 4
#define H 64
#define STEPS 60
#define M_BLK 16       // batch rows per block
#define M 8            // rows per chain
#define MR 8           // LDS rows per chain buffer
#define A0S 104        // halves/row: [x(4) | h0(64) | zero-pad]
#define A1S 136        // halves/row: [h0(64) | h1(64)] + slack
#define A0P (MR * A0S)
#define A1P (MR * A1S)
#define XN (M_BLK * T_ENC * D_IN)   // 8192 halves
#define NTHREADS 1024

typedef _Float16 half8 __attribute__((ext_vector_type(8)));
typedef _Float16 half4_t __attribute__((ext_vector_type(4)));
typedef float float4v __attribute__((ext_vector_type(4)));
typedef unsigned uint2v __attribute__((ext_vector_type(2)));

// Two-sided partition pins (empty asm -> no code, class constraint only).
#define PIN_AGPR(v8) asm("" : "+a"(v8))   // -> AccVGPR half (weights)
#define PIN_VGPR(v4) asm("" : "+v"(v4))   // -> ArchVGPR half (accumulators)

__device__ __forceinline__ float fast_sigmoid(float x) {
    float e = __builtin_amdgcn_exp2f(-1.44269504f * x);
    return __builtin_amdgcn_rcpf(1.0f + e);
}
__device__ __forceinline__ float fast_tanh(float x) {
    float e = __builtin_amdgcn_exp2f(2.88539008f * x);   // exp(2x)
    return __builtin_fmaf(-2.0f, __builtin_amdgcn_rcpf(e + 1.0f), 1.0f);
}

// v_permlane32_swap_b32: result.x = [a lanes0-31 | b lanes0-31]
__device__ __forceinline__ float take_lo_pair(float a, float b) {
    uint2v r = __builtin_amdgcn_permlane32_swap(
        __builtin_bit_cast(unsigned, a), __builtin_bit_cast(unsigned, b),
        false, false);
    return __builtin_bit_cast(float, r.x);
}

// Redistribute a 16x16 C tile (valid rows 0-7 live in lanes 0-31) so each
// lane handles rows (rowA, rowA+1) at its column, then run the LSTM cell.
// rowA = quad<2 ? 4*quad : 4*(quad-2)+2.  (verified passing, rounds 1-5)
__device__ __forceinline__ void lstm_epi(const float4v C[4], float cs[2],
                                         _Float16* h_a, _Float16* h_b) {
    float ga[4], gb[4];
    #pragma unroll
    for (int tau = 0; tau < 4; ++tau) {
        ga[tau] = take_lo_pair(C[tau][0], C[tau][2]);   // rows {0,4 | 2,6}
        gb[tau] = take_lo_pair(C[tau][1], C[tau][3]);   // rows {1,5 | 3,7}
    }
    {
        const float ig = fast_sigmoid(ga[0]);
        const float fg = fast_sigmoid(ga[1]);
        const float gg = fast_tanh   (ga[2]);
        const float og = fast_sigmoid(ga[3]);
        const float c  = fg * cs[0] + ig * gg;
        cs[0] = c;
        *h_a = (_Float16)(og * fast_tanh(c));
    }
    {
        const float ig = fast_sigmoid(gb[0]);
        const float fg = fast_sigmoid(gb[1]);
        const float gg = fast_tanh   (gb[2]);
        const float og = fast_sigmoid(gb[3]);
        const float c  = fg * cs[1] + ig * gg;
        cs[1] = c;
        *h_b = (_Float16)(og * fast_tanh(c));
    }
}

__global__ __launch_bounds__(NTHREADS, 1) void lstm_ar_kernel(
    const float* __restrict__ x,
    const float* __restrict__ Wih0, const float* __restrict__ Whh0,
    const float* __restrict__ bih0, const float* __restrict__ bhh0,
    const float* __restrict__ Wih1, const float* __restrict__ Whh1,
    const float* __restrict__ bih1, const float* __restrict__ bhh1,
    const float* __restrict__ Wfc,  const float* __restrict__ bfc,
    float* __restrict__ out)
{
    __shared__ __align__(16) _Float16 A0buf[2][2 * A0P];   // [chain][pp*A0P]
    __shared__ __align__(16) _Float16 A1buf[2][2 * A1P];   // [chain][pp*A1P]
    __shared__ __align__(16) _Float16 xAll[XN];            // [elem][t][d] fp16
    __shared__ __align__(16) _Float16 WfcS[2][64 * 8];     // head B-frags (2KB)
    __shared__ __align__(16) float    predsS[M_BLK * STEPS * D_IN];

    const int tid   = threadIdx.x;
    const int wave  = tid >> 6;        // 0..15
    const int lane  = tid & 63;
    const int n16   = lane & 15;
    const int quad  = lane >> 4;
    const int chain = wave >> 3;       // 0: rows 0-7, 1: rows 8-15
    const int grp   = (wave >> 2) & 1; // 0: layer-1 wave, 1: layer-0 wave
    const int w4    = wave & 3;        // colgroup; also the SIMD id
    const int m0    = blockIdx.x * M_BLK;
    const int m     = n16 & 7;         // A-frag row (rows 8-15 dup -> broadcast)
    const int jcol  = 16 * w4 + n16;   // hidden column owned in epilogues
    const int rowA  = (quad < 2) ? (quad * 4) : ((quad - 2) * 4 + 2);

    _Float16* A0 = &A0buf[chain][0];
    _Float16* A1 = &A1buf[chain][0];

    { _Float16* z = &A0buf[0][0]; for (int i = tid; i < 2 * 2 * A0P; i += NTHREADS) z[i] = (_Float16)0.f; }
    { _Float16* z = &A1buf[0][0]; for (int i = tid; i < 2 * 2 * A1P; i += NTHREADS) z[i] = (_Float16)0.f; }
    // x -> fp16 LDS (one-time; removes all global loads from the main loop)
    for (int j = tid; j < XN / 4; j += NTHREADS) {
        const float4v v = *(const float4v*)&x[(size_t)m0 * T_ENC * D_IN + (size_t)j * 4];
        *(half4_t*)&xAll[j * 4] =
            (half4_t){(_Float16)v[0], (_Float16)v[1], (_Float16)v[2], (_Float16)v[3]};
    }
    // head weight fragments -> LDS (keeps head wave's arch demand low)
    if (tid < 128) {
        const int kt = tid >> 6, l = tid & 63;
        const int nn = l & 15, qq = l >> 4;
        half8 v;
        #pragma unroll
        for (int j = 0; j < 8; ++j) {
            const int k = kt * 32 + qq * 8 + j;
            v[j] = (_Float16)((nn < 4) ? Wfc[nn * H + k] : 0.f);
        }
        *(half8*)&WfcS[kt][l * 8] = v;
    }

    // ---- SHARED weight fragments: Bw[k][n], n = 64*tau + jcol ----
    // grp0: layer1, K=128 = [h0 | h1] (4 kt).  grp1: layer0 encode, K=96
    // (3 kt used; kt=3 zero-filled so the AGPR pin never sees undef).
    half8 Bw[4][4];
    float bias[4];
    float bfcv = 0.f;
    if (grp == 0) {
        #pragma unroll
        for (int tau = 0; tau < 4; ++tau) {
            const int n = 64 * tau + jcol;
            bias[tau] = bih1[n] + bhh1[n];
            #pragma unroll
            for (int kt = 0; kt < 4; ++kt) {
                #pragma unroll
                for (int j = 0; j < 8; ++j) {
                    const int k = kt * 32 + quad * 8 + j;
                    Bw[kt][tau][j] = (_Float16)((k < H) ? Wih1[n * H + k] : Whh1[n * H + (k - H)]);
                }
                PIN_AGPR(Bw[kt][tau]);
            }
        }
    } else {
        #pragma unroll
        for (int tau = 0; tau < 4; ++tau) {
            const int n = 64 * tau + jcol;
            bias[tau] = bih0[n] + bhh0[n];
            #pragma unroll
            for (int kt = 0; kt < 4; ++kt) {
                #pragma unroll
                for (int j = 0; j < 8; ++j) {
                    const int k = kt * 32 + quad * 8 + j;
                    float v = 0.f;
                    if (k < 4)       v = Wih0[n * D_IN + k];
                    else if (k < 68) v = Whh0[n * H + (k - 4)];
                    Bw[kt][tau][j] = (_Float16)v;
                }
                PIN_AGPR(Bw[kt][tau]);
            }
        }
        if (w4 == 0 && n16 < 4) bfcv = bfc[n16];
    }

    float cs[2] = {0.f, 0.f};   // cell state for rows (rowA, rowA+1) @ jcol
    // ONE accumulator array for the whole kernel (prologue/encode/AR).
    float4v Cpre[4];

    __syncthreads();   // LDS zero + xAll + WfcS ready

    // x(0) -> A0[pp=1] x-slot (prologue input); x(1) -> A0[pp=0] (iter-0 input)
    if (grp == 1 && w4 == 2 && lane < 8) {
        const int elem = chain * 8 + lane;
        *(half4_t*)&A0[A0P + lane * A0S] = *(const half4_t*)&xAll[(elem * T_ENC + 0) * D_IN];
        *(half4_t*)&A0[lane * A0S]       = *(const half4_t*)&xAll[(elem * T_ENC + 1) * D_IN];
    }
    __syncthreads();

    // ---- prologue: L0 step 0 (grp1 only) ----
    if (grp == 1) {
        half8 af[3];
        #pragma unroll
        for (int kt = 0; kt < 3; ++kt)
            af[kt] = *(const half8*)&A0[A0P + m * A0S + kt * 32 + quad * 8];
        #pragma unroll
        for (int tau = 0; tau < 4; ++tau) {
            Cpre[tau] = (float4v){bias[tau], bias[tau], bias[tau], bias[tau]};
            PIN_VGPR(Cpre[tau]);
        }
        #pragma unroll
        for (int kt = 0; kt < 3; ++kt)
            #pragma unroll
            for (int tau = 0; tau < 4; ++tau)
                Cpre[tau] = __builtin_amdgcn_mfma_f32_16x16x32_f16(af[kt], Bw[kt][tau], Cpre[tau], 0, 0, 0);
        _Float16 ha, hb;
        lstm_epi(Cpre, cs, &ha, &hb);
        A1[rowA * A1S + jcol]           = ha;
        A1[(rowA + 1) * A1S + jcol]     = hb;
        A0[rowA * A0S + 4 + jcol]       = ha;
        A0[(rowA + 1) * A0S + 4 + jcol] = hb;
    }
    __syncthreads();

    // ---- encode: iter t = L1(t) on grp0  ||  L0(t+1) on grp1; 1 barrier ----
    for (int t = 0; t < T_ENC; ++t) {
        const int p = t & 1;
        if (grp == 0) {
            const _Float16* cur1 = A1 + p * A1P;
            _Float16* nxt1 = A1 + (1 - p) * A1P;
            half8 af[4];
            #pragma unroll
            for (int kt = 0; kt < 4; ++kt)
                af[kt] = *(const half8*)&cur1[m * A1S + kt * 32 + quad * 8];
            #pragma unroll
            for (int tau = 0; tau < 4; ++tau) {
                Cpre[tau] = (float4v){bias[tau], bias[tau], bias[tau], bias[tau]};
                PIN_VGPR(Cpre[tau]);
            }
            #pragma unroll
            for (int kt = 0; kt < 4; ++kt)
                #pragma unroll
                for (int tau = 0; tau < 4; ++tau)
                    Cpre[tau] = __builtin_amdgcn_mfma_f32_16x16x32_f16(af[kt], Bw[kt][tau], Cpre[tau], 0, 0, 0);
            _Float16 ha, hb;
            lstm_epi(Cpre, cs, &ha, &hb);
            nxt1[rowA * A1S + 64 + jcol]       = ha;
            nxt1[(rowA + 1) * A1S + 64 + jcol] = hb;
        } else {
            const _Float16* cur0 = A0 + p * A0P;
            _Float16* nxt0 = A0 + (1 - p) * A0P;
            _Float16* nxt1 = A1 + (1 - p) * A1P;
            half8 af[3];
            #pragma unroll
            for (int kt = 0; kt < 3; ++kt)
                af[kt] = *(const half8*)&cur0[m * A0S + kt * 32 + quad * 8];
            #pragma unroll
            for (int tau = 0; tau < 4; ++tau) {
                Cpre[tau] = (float4v){bias[tau], bias[tau], bias[tau], bias[tau]};
                PIN_VGPR(Cpre[tau]);
            }
            #pragma unroll
            for (int kt = 0; kt < 3; ++kt)
                #pragma unroll
                for (int tau = 0; tau < 4; ++tau)
                    Cpre[tau] = __builtin_amdgcn_mfma_f32_16x16x32_f16(af[kt], Bw[kt][tau], Cpre[tau], 0, 0, 0);
            _Float16 ha, hb;
            lstm_epi(Cpre, cs, &ha, &hb);
            nxt1[rowA * A1S + jcol]           = ha;
            nxt1[(rowA + 1) * A1S + jcol]     = hb;
            nxt0[rowA * A0S + 4 + jcol]       = ha;
            nxt0[(rowA + 1) * A0S + 4 + jcol] = hb;
            if (w4 == 2 && lane < 8) {         // x(t+2) -> nxt0 x-slot
                int tn = t + 2; if (tn > T_ENC - 1) tn = T_ENC - 1;
                *(half4_t*)&nxt0[lane * A0S] =
                    *(const half4_t*)&xAll[((chain * 8 + lane) * T_ENC + tn) * D_IN];
            }
        }
        __syncthreads();
    }

    // ---- AR switch: grp1 REWRITES Bw in place -> [Whh0 | Wih0@Wfc],
    //      bias += Wih0·bfc; re-pin each fragment into AGPRs ----
    if (grp == 1) {
        #pragma unroll
        for (int tau = 0; tau < 4; ++tau) {
            const int n = 64 * tau + jcol;
            float wb = 0.f;
            #pragma unroll
            for (int d = 0; d < 4; ++d) wb += Wih0[n * D_IN + d] * bfc[d];
            bias[tau] += wb;
            #pragma unroll
            for (int kt = 0; kt < 4; ++kt) {
                #pragma unroll
                for (int j = 0; j < 8; ++j) {
                    const int k = kt * 32 + quad * 8 + j;
                    float v;
                    if (k < H) v = Whh0[n * H + k];
                    else {
                        const int c = k - H;
                        v = Wih0[n * D_IN + 0] * Wfc[0 * H + c] + Wih0[n * D_IN + 1] * Wfc[1 * H + c]
                          + Wih0[n * D_IN + 2] * Wfc[2 * H + c] + Wih0[n * D_IN + 3] * Wfc[3 * H + c];
                    }
                    Bw[kt][tau][j] = (_Float16)v;
                }
                PIN_AGPR(Bw[kt][tau]);
            }
        }
    }
    // grp0 prologue: Cpre = b1 + Whh1·h1(127)  (carried into the AR loop)
    if (grp == 0) {
        half8 ah[2];
        #pragma unroll
        for (int kt = 0; kt < 2; ++kt)
            ah[kt] = *(const half8*)&A1[m * A1S + 64 + kt * 32 + quad * 8];
        #pragma unroll
        for (int tau = 0; tau < 4; ++tau) {
            Cpre[tau] = (float4v){bias[tau], bias[tau], bias[tau], bias[tau]};
            PIN_VGPR(Cpre[tau]);
        }
        #pragma unroll
        for (int kt = 0; kt < 2; ++kt)
            #pragma unroll
            for (int tau = 0; tau < 4; ++tau)
                Cpre[tau] = __builtin_amdgcn_mfma_f32_16x16x32_f16(ah[kt], Bw[2 + kt][tau], Cpre[tau], 0, 0, 0);
    }

    // ---- AR: phase1 = L1 finish (grp0) || Whh0-part (grp1); B1;
    //          phase2 = L0ar finish + head (grp1) || Whh1-part (grp0); B2 ----
    for (int s = 0; s < STEPS; ++s) {
        const int q = s & 1;
        const _Float16* cur = A1 + q * A1P;
        _Float16* nxt = A1 + (1 - q) * A1P;

        {
            half8 ah0[2];   // h0(s)
            #pragma unroll
            for (int kt = 0; kt < 2; ++kt)
                ah0[kt] = *(const half8*)&cur[m * A1S + kt * 32 + quad * 8];

            if (grp == 0) {
                #pragma unroll
                for (int kt = 0; kt < 2; ++kt)
                    #pragma unroll
                    for (int tau = 0; tau < 4; ++tau)
                        Cpre[tau] = __builtin_amdgcn_mfma_f32_16x16x32_f16(ah0[kt], Bw[kt][tau], Cpre[tau], 0, 0, 0);
                _Float16 ha, hb;
                lstm_epi(Cpre, cs, &ha, &hb);
                nxt[rowA * A1S + 64 + jcol]       = ha;
                nxt[(rowA + 1) * A1S + 64 + jcol] = hb;
            } else {
                #pragma unroll
                for (int tau = 0; tau < 4; ++tau) {
                    Cpre[tau] = (float4v){bias[tau], bias[tau], bias[tau], bias[tau]};
                    PIN_VGPR(Cpre[tau]);
                }
                #pragma unroll
                for (int kt = 0; kt < 2; ++kt)
                    #pragma unroll
                    for (int tau = 0; tau < 4; ++tau)
                        Cpre[tau] = __builtin_amdgcn_mfma_f32_16x16x32_f16(ah0[kt], Bw[kt][tau], Cpre[tau], 0, 0, 0);
            }
        }
        __syncthreads();   // B1: h1(s) visible

        {
            half8 ah1[2];   // h1(s)
            #pragma unroll
            for (int kt = 0; kt < 2; ++kt)
                ah1[kt] = *(const half8*)&nxt[m * A1S + 64 + kt * 32 + quad * 8];

            if (grp == 1) {
                #pragma unroll
                for (int kt = 0; kt < 2; ++kt)
                    #pragma unroll
                    for (int tau = 0; tau < 4; ++tau)
                        Cpre[tau] = __builtin_amdgcn_mfma_f32_16x16x32_f16(ah1[kt], Bw[2 + kt][tau], Cpre[tau], 0, 0, 0);
                if (w4 == 0) {   // head: pred(s) = Wfc·h1(s)+bfc, off critical path
                    half8 bf0 = *(const half8*)&WfcS[0][lane * 8];
                    half8 bf1 = *(const half8*)&WfcS[1][lane * 8];
                    float4v Cp = (float4v){bfcv, bfcv, bfcv, bfcv};
                    PIN_VGPR(Cp);
                    Cp = __builtin_amdgcn_mfma_f32_16x16x32_f16(ah1[0], bf0, Cp, 0, 0, 0);
                    Cp = __builtin_amdgcn_mfma_f32_16x16x32_f16(ah1[1], bf1, Cp, 0, 0, 0);
                    if (n16 < 4 && quad < 2) {     // valid rows 0-7 live in quads 0-1
                        #pragma unroll
                        for (int r = 0; r < 4; ++r)
                            predsS[(chain * 8 + quad * 4 + r) * (STEPS * D_IN) + s * D_IN + n16] = Cp[r];
                    }
                }
                _Float16 ha, hb;
                lstm_epi(Cpre, cs, &ha, &hb);
                nxt[rowA * A1S + jcol]           = ha;
                nxt[(rowA + 1) * A1S + jcol]     = hb;
            } else {   // grp0 pre-computes Cpre(s+1) = b1 + Whh1·h1(s)
                #pragma unroll
                for (int tau = 0; tau < 4; ++tau) {
                    Cpre[tau] = (float4v){bias[tau], bias[tau], bias[tau], bias[tau]};
                    PIN_VGPR(Cpre[tau]);
                }
                #pragma unroll
                for (int kt = 0; kt < 2; ++kt)
                    #pragma unroll
                    for (int tau = 0; tau < 4; ++tau)
                        Cpre[tau] = __builtin_amdgcn_mfma_f32_16x16x32_f16(ah1[kt], Bw[2 + kt][tau], Cpre[tau], 0, 0, 0);
            }
        }
        __syncthreads();   // B2: h0(s+1) visible
    }

    // ---- bulk store preds ----
    for (int j = tid; j < M_BLK * STEPS; j += NTHREADS) {
        const int elem = j / STEPS, r = j - elem * STEPS;
        ((float4v*)out)[(size_t)(m0 + elem) * STEPS + r] = ((const float4v*)predsS)[j];
    }
}

extern "C" void kernel_launch(void* const* d_in, const int* in_sizes, int n_in,
                              void* d_out, int out_size, void* d_ws, size_t ws_size,
                              hipStream_t stream) {
    const float* x    = (const float*)d_in[0];
    const float* Wih0 = (const float*)d_in[1];
    const float* Whh0 = (const float*)d_in[2];
    const float* bih0 = (const float*)d_in[3];
    const float* bhh0 = (const float*)d_in[4];
    const float* Wih1 = (const float*)d_in[5];
    const float* Whh1 = (const float*)d_in[6];
    const float* bih1 = (const float*)d_in[7];
    const float* bhh1 = (const float*)d_in[8];
    const float* Wfc  = (const float*)d_in[9];
    const float* bfc  = (const float*)d_in[10];
    float* out = (float*)d_out;

    dim3 grid(4096 / M_BLK);   // 256 blocks, one per CU
    dim3 block(NTHREADS);      // 16 waves = 4/SIMD: {c0L1,c0L0,c1L1,c1L0}
    lstm_ar_kernel<<<grid, block, 0, stream>>>(
        x, Wih0, Whh0, bih0, bhh0, Wih1, Whh1, bih1, bhh1, Wfc, bfc, out);
}

// Round 7
// 279.746 us; speedup vs baseline: 2.9232x; 2.9232x over previous
//
#include <hip/hip_runtime.h>

// 2-layer LSTM (H=64) encode(128) + AR(60), B=4096, persistent per-block.
// ROUND-7: 256 blocks x 768 threads (12 waves), M=16 rows, ONE chain,
// 3 waves/SIMD: {L1-half0, L1-half1, L0} per SIMD.
//   waves 0-7 : L1, split into halves. Both halves of a column-group run
//               the IDENTICAL 16 MFMAs (dup; matrix pipe has headroom) but
//               each epilogues only 2 of the 4 C-regs (half0: r=0,1;
//               half1: r=2,3) -> L1's serial activation chain halves and
//               each SIMD gets a 3rd independent stream to fill stalls.
//   waves 8-11: L0, full 4-row epilogue (round-0 structure, verified).
// __launch_bounds__(768,3) -> reg budget 170/wave, ABOVE the ~155 natural
// demand measured in the spill-free rounds 0/2 -> no allocator squeeze.
// (Rounds 4-6 lesson: any budget <= 128 total makes hipcc hard-split
// 64 arch + 64 acc and spill; pins make it worse. Never again.)
// Register hygiene (round-6's verified-correct merges, no pins):
//   - ONE Bw[4][4] weight array per wave; grp1 rewrites it in place to
//     [Whh0 | Wih0@Wfc] at the AR switch (bias += Wih0·bfc).
//   - ONE Cacc[4] accumulator reused across prologue/encode/AR.
//   - Head weights in a 2KB LDS table (WfcS).
// Per-row arithmetic identical to rounds 0-6 (all passed, same absmax).

#define T_ENC 128
#define D_IN 4
#define H 64
#define STEPS 60
#define M_BLK 16
#define A0S 104        // halves/row: [x(4) | h0(64) | zero-pad]
#define A1S 136        // halves/row: [h0(64) | h1(64)] + slack
#define A0P (M_BLK * A0S)
#define A1P (M_BLK * A1S)
#define XN (M_BLK * T_ENC * D_IN)   // 8192 halves
#define NTHREADS 768

typedef _Float16 half8 __attribute__((ext_vector_type(8)));
typedef _Float16 half4_t __attribute__((ext_vector_type(4)));
typedef float float4v __attribute__((ext_vector_type(4)));

__device__ __forceinline__ float fast_sigmoid(float x) {
    float e = __builtin_amdgcn_exp2f(-1.44269504f * x);
    return __builtin_amdgcn_rcpf(1.0f + e);
}
__device__ __forceinline__ float fast_tanh(float x) {
    float e = __builtin_amdgcn_exp2f(2.88539008f * x);   // exp(2x)
    return __builtin_fmaf(-2.0f, __builtin_amdgcn_rcpf(e + 1.0f), 1.0f);
}

// One LSTM cell update (identical op order to the round-0..6 passing
// kernels: ig,fg,gg,og -> c = fg*c + ig*gg -> h = og*tanh(c)).
__device__ __forceinline__ _Float16 cell_h(float gi, float gf, float gg,
                                           float go, float* c) {
    const float ig = fast_sigmoid(gi);
    const float fg = fast_sigmoid(gf);
    const float g  = fast_tanh   (gg);
    const float og = fast_sigmoid(go);
    const float cn = fg * (*c) + ig * g;
    *c = cn;
    return (_Float16)(og * fast_tanh(cn));
}

__global__ __launch_bounds__(NTHREADS, 3) void lstm_ar_kernel(
    const float* __restrict__ x,
    const float* __restrict__ Wih0, const float* __restrict__ Whh0,
    const float* __restrict__ bih0, const float* __restrict__ bhh0,
    const float* __restrict__ Wih1, const float* __restrict__ Whh1,
    const float* __restrict__ bih1, const float* __restrict__ bhh1,
    const float* __restrict__ Wfc,  const float* __restrict__ bfc,
    float* __restrict__ out)
{
    __shared__ __align__(16) _Float16 A0buf[2 * A0P];
    __shared__ __align__(16) _Float16 A1buf[2 * A1P];
    __shared__ __align__(16) _Float16 xAll[XN];            // [elem][t][d] fp16
    __shared__ __align__(16) _Float16 WfcS[2][64 * 8];     // head B-frags (2KB)
    __shared__ __align__(16) float    predsS[M_BLK * STEPS * D_IN];

    const int tid  = threadIdx.x;
    const int wave = tid >> 6;         // 0..11
    const int lane = tid & 63;
    const int n16  = lane & 15;
    const int quad = lane >> 4;
    const int grp  = (wave >= 8) ? 1 : 0;   // 0: L1 half-waves, 1: L0 waves
    const int w4   = grp ? (wave - 8) : (wave & 3);   // column group = SIMD id
    const int hf   = grp ? 0 : (wave >> 2);           // L1 half: regs {0,1} or {2,3}
    const int m0   = blockIdx.x * M_BLK;
    const int m    = n16;              // A-frag row (batch element)
    const int jcol = 16 * w4 + n16;    // hidden column owned in epilogues

    { for (int i = tid; i < 2 * A0P; i += NTHREADS) A0buf[i] = (_Float16)0.f; }
    { for (int i = tid; i < 2 * A1P; i += NTHREADS) A1buf[i] = (_Float16)0.f; }
    // x -> fp16 LDS (one-time; removes all global loads from the main loop)
    for (int j = tid; j < XN / 4; j += NTHREADS) {
        const float4v v = *(const float4v*)&x[(size_t)m0 * T_ENC * D_IN + (size_t)j * 4];
        *(half4_t*)&xAll[j * 4] =
            (half4_t){(_Float16)v[0], (_Float16)v[1], (_Float16)v[2], (_Float16)v[3]};
    }
    // head weight fragments -> LDS
    if (tid < 128) {
        const int kt = tid >> 6, l = tid & 63;
        const int nn = l & 15, qq = l >> 4;
        half8 v;
        #pragma unroll
        for (int j = 0; j < 8; ++j) {
            const int k = kt * 32 + qq * 8 + j;
            v[j] = (_Float16)((nn < 4) ? Wfc[nn * H + k] : 0.f);
        }
        *(half8*)&WfcS[kt][l * 8] = v;
    }

    // ---- per-wave weight fragments: Bw[kt][tau], col n = 64*tau + jcol ----
    // grp0: layer1, K=128 = [h0 | h1].  grp1: layer0 encode, K=96+pad
    // (kt=3 fills zeros via the k<68 guard).
    half8 Bw[4][4];
    float bias[4];
    float bfcv = 0.f;
    if (grp == 0) {
        #pragma unroll
        for (int tau = 0; tau < 4; ++tau) {
            const int n = 64 * tau + jcol;
            bias[tau] = bih1[n] + bhh1[n];
            #pragma unroll
            for (int kt = 0; kt < 4; ++kt)
                #pragma unroll
                for (int j = 0; j < 8; ++j) {
                    const int k = kt * 32 + quad * 8 + j;
                    Bw[kt][tau][j] = (_Float16)((k < H) ? Wih1[n * H + k] : Whh1[n * H + (k - H)]);
                }
        }
    } else {
        #pragma unroll
        for (int tau = 0; tau < 4; ++tau) {
            const int n = 64 * tau + jcol;
            bias[tau] = bih0[n] + bhh0[n];
            #pragma unroll
            for (int kt = 0; kt < 4; ++kt)
                #pragma unroll
                for (int j = 0; j < 8; ++j) {
                    const int k = kt * 32 + quad * 8 + j;
                    float v = 0.f;
                    if (k < 4)       v = Wih0[n * D_IN + k];
                    else if (k < 68) v = Whh0[n * H + (k - 4)];
                    Bw[kt][tau][j] = (_Float16)v;
                }
        }
        if (w4 == 0 && n16 < 4) bfcv = bfc[n16];
    }

    float csv[4] = {0.f, 0.f, 0.f, 0.f};   // cell state (grp0 uses [0..1])
    float4v Cacc[4];                        // the ONE accumulator array

    __syncthreads();   // LDS zero + xAll + WfcS ready

    // x(0) -> A0[pp=1] x-slot (prologue input); x(1) -> A0[pp=0] (iter-0 input)
    if (grp == 1 && w4 == 2 && lane < 16) {
        *(half4_t*)&A0buf[A0P + lane * A0S] = *(const half4_t*)&xAll[(lane * T_ENC + 0) * D_IN];
        *(half4_t*)&A0buf[lane * A0S]       = *(const half4_t*)&xAll[(lane * T_ENC + 1) * D_IN];
    }
    __syncthreads();

    // ---- prologue: L0 step 0 (grp1 only) ----
    if (grp == 1) {
        half8 af[3];
        #pragma unroll
        for (int kt = 0; kt < 3; ++kt)
            af[kt] = *(const half8*)&A0buf[A0P + m * A0S + kt * 32 + quad * 8];
        #pragma unroll
        for (int tau = 0; tau < 4; ++tau)
            Cacc[tau] = (float4v){bias[tau], bias[tau], bias[tau], bias[tau]};
        #pragma unroll
        for (int kt = 0; kt < 3; ++kt)
            #pragma unroll
            for (int tau = 0; tau < 4; ++tau)
                Cacc[tau] = __builtin_amdgcn_mfma_f32_16x16x32_f16(af[kt], Bw[kt][tau], Cacc[tau], 0, 0, 0);
        #pragma unroll
        for (int r = 0; r < 4; ++r) {
            const _Float16 h = cell_h(Cacc[0][r], Cacc[1][r], Cacc[2][r], Cacc[3][r], &csv[r]);
            const int row = quad * 4 + r;
            A1buf[row * A1S + jcol]     = h;
            A0buf[row * A0S + 4 + jcol] = h;
        }
    }
    __syncthreads();

    // ---- encode: iter t = L1(t) on grp0-halves  ||  L0(t+1) on grp1 ----
    for (int t = 0; t < T_ENC; ++t) {
        const int p = t & 1;
        if (grp == 0) {
            const _Float16* cur1 = A1buf + p * A1P;
            _Float16* nxt1 = A1buf + (1 - p) * A1P;
            half8 af[4];
            #pragma unroll
            for (int kt = 0; kt < 4; ++kt)
                af[kt] = *(const half8*)&cur1[m * A1S + kt * 32 + quad * 8];
            #pragma unroll
            for (int tau = 0; tau < 4; ++tau)
                Cacc[tau] = (float4v){bias[tau], bias[tau], bias[tau], bias[tau]};
            #pragma unroll
            for (int kt = 0; kt < 4; ++kt)
                #pragma unroll
                for (int tau = 0; tau < 4; ++tau)
                    Cacc[tau] = __builtin_amdgcn_mfma_f32_16x16x32_f16(af[kt], Bw[kt][tau], Cacc[tau], 0, 0, 0);
            // half-split epilogue: constant-index extracts, cndmask on hf
            float g0[4], g1[4];
            #pragma unroll
            for (int tau = 0; tau < 4; ++tau) {
                g0[tau] = hf ? Cacc[tau][2] : Cacc[tau][0];
                g1[tau] = hf ? Cacc[tau][3] : Cacc[tau][1];
            }
            const int row0 = quad * 4 + hf * 2;
            const _Float16 ha = cell_h(g0[0], g0[1], g0[2], g0[3], &csv[0]);
            const _Float16 hb = cell_h(g1[0], g1[1], g1[2], g1[3], &csv[1]);
            nxt1[row0 * A1S + 64 + jcol]       = ha;
            nxt1[(row0 + 1) * A1S + 64 + jcol] = hb;
        } else {
            const _Float16* cur0 = A0buf + p * A0P;
            _Float16* nxt0 = A0buf + (1 - p) * A0P;
            _Float16* nxt1 = A1buf + (1 - p) * A1P;
            half8 af[3];
            #pragma unroll
            for (int kt = 0; kt < 3; ++kt)
                af[kt] = *(const half8*)&cur0[m * A0S + kt * 32 + quad * 8];
            #pragma unroll
            for (int tau = 0; tau < 4; ++tau)
                Cacc[tau] = (float4v){bias[tau], bias[tau], bias[tau], bias[tau]};
            #pragma unroll
            for (int kt = 0; kt < 3; ++kt)
                #pragma unroll
                for (int tau = 0; tau < 4; ++tau)
                    Cacc[tau] = __builtin_amdgcn_mfma_f32_16x16x32_f16(af[kt], Bw[kt][tau], Cacc[tau], 0, 0, 0);
            #pragma unroll
            for (int r = 0; r < 4; ++r) {
                const _Float16 h = cell_h(Cacc[0][r], Cacc[1][r], Cacc[2][r], Cacc[3][r], &csv[r]);
                const int row = quad * 4 + r;
                nxt1[row * A1S + jcol]     = h;
                nxt0[row * A0S + 4 + jcol] = h;
            }
            if (w4 == 2 && lane < 16) {        // x(t+2) -> nxt0 x-slot
                int tn = t + 2; if (tn > T_ENC - 1) tn = T_ENC - 1;
                *(half4_t*)&nxt0[lane * A0S] = *(const half4_t*)&xAll[(lane * T_ENC + tn) * D_IN];
            }
        }
        __syncthreads();
    }

    // ---- AR switch: grp1 REWRITES Bw in place -> [Whh0 | Wih0@Wfc],
    //      bias += Wih0·bfc.  grp0 overlaps: Cacc = b1 + Whh1·h1(127). ----
    if (grp == 1) {
        #pragma unroll
        for (int tau = 0; tau < 4; ++tau) {
            const int n = 64 * tau + jcol;
            float wb = 0.f;
            #pragma unroll
            for (int d = 0; d < 4; ++d) wb += Wih0[n * D_IN + d] * bfc[d];
            bias[tau] += wb;
            #pragma unroll
            for (int kt = 0; kt < 4; ++kt)
                #pragma unroll
                for (int j = 0; j < 8; ++j) {
                    const int k = kt * 32 + quad * 8 + j;
                    float v;
                    if (k < H) v = Whh0[n * H + k];
                    else {
                        const int c = k - H;
                        v = Wih0[n * D_IN + 0] * Wfc[0 * H + c] + Wih0[n * D_IN + 1] * Wfc[1 * H + c]
                          + Wih0[n * D_IN + 2] * Wfc[2 * H + c] + Wih0[n * D_IN + 3] * Wfc[3 * H + c];
                    }
                    Bw[kt][tau][j] = (_Float16)v;
                }
        }
    } else {
        half8 ah[2];
        #pragma unroll
        for (int kt = 0; kt < 2; ++kt)
            ah[kt] = *(const half8*)&A1buf[m * A1S + 64 + kt * 32 + quad * 8];
        #pragma unroll
        for (int tau = 0; tau < 4; ++tau)
            Cacc[tau] = (float4v){bias[tau], bias[tau], bias[tau], bias[tau]};
        #pragma unroll
        for (int kt = 0; kt < 2; ++kt)
            #pragma unroll
            for (int tau = 0; tau < 4; ++tau)
                Cacc[tau] = __builtin_amdgcn_mfma_f32_16x16x32_f16(ah[kt], Bw[2 + kt][tau], Cacc[tau], 0, 0, 0);
    }

    // ---- AR: phase1 = L1 finish (grp0-halves) || Whh0-part (grp1); B1;
    //          phase2 = L0ar finish + head (grp1) || Whh1-pre (grp0); B2 ----
    for (int s = 0; s < STEPS; ++s) {
        const int q = s & 1;
        const _Float16* cur = A1buf + q * A1P;
        _Float16* nxt = A1buf + (1 - q) * A1P;

        {
            half8 ah0[2];   // h0(s)
            #pragma unroll
            for (int kt = 0; kt < 2; ++kt)
                ah0[kt] = *(const half8*)&cur[m * A1S + kt * 32 + quad * 8];

            if (grp == 0) {
                #pragma unroll
                for (int kt = 0; kt < 2; ++kt)
                    #pragma unroll
                    for (int tau = 0; tau < 4; ++tau)
                        Cacc[tau] = __builtin_amdgcn_mfma_f32_16x16x32_f16(ah0[kt], Bw[kt][tau], Cacc[tau], 0, 0, 0);
                float g0[4], g1[4];
                #pragma unroll
                for (int tau = 0; tau < 4; ++tau) {
                    g0[tau] = hf ? Cacc[tau][2] : Cacc[tau][0];
                    g1[tau] = hf ? Cacc[tau][3] : Cacc[tau][1];
                }
                const int row0 = quad * 4 + hf * 2;
                const _Float16 ha = cell_h(g0[0], g0[1], g0[2], g0[3], &csv[0]);
                const _Float16 hb = cell_h(g1[0], g1[1], g1[2], g1[3], &csv[1]);
                nxt[row0 * A1S + 64 + jcol]       = ha;
                nxt[(row0 + 1) * A1S + 64 + jcol] = hb;
            } else {
                #pragma unroll
                for (int tau = 0; tau < 4; ++tau)
                    Cacc[tau] = (float4v){bias[tau], bias[tau], bias[tau], bias[tau]};
                #pragma unroll
                for (int kt = 0; kt < 2; ++kt)
                    #pragma unroll
                    for (int tau = 0; tau < 4; ++tau)
                        Cacc[tau] = __builtin_amdgcn_mfma_f32_16x16x32_f16(ah0[kt], Bw[kt][tau], Cacc[tau], 0, 0, 0);
            }
        }
        __syncthreads();   // B1: h1(s) visible

        {
            half8 ah1[2];   // h1(s)
            #pragma unroll
            for (int kt = 0; kt < 2; ++kt)
                ah1[kt] = *(const half8*)&nxt[m * A1S + 64 + kt * 32 + quad * 8];

            if (grp == 1) {
                #pragma unroll
                for (int kt = 0; kt < 2; ++kt)
                    #pragma unroll
                    for (int tau = 0; tau < 4; ++tau)
                        Cacc[tau] = __builtin_amdgcn_mfma_f32_16x16x32_f16(ah1[kt], Bw[2 + kt][tau], Cacc[tau], 0, 0, 0);
                if (w4 == 0) {   // head: pred(s) = Wfc·h1(s)+bfc, off critical path
                    half8 bf0 = *(const half8*)&WfcS[0][lane * 8];
                    half8 bf1 = *(const half8*)&WfcS[1][lane * 8];
                    float4v Cp = (float4v){bfcv, bfcv, bfcv, bfcv};
                    Cp = __builtin_amdgcn_mfma_f32_16x16x32_f16(ah1[0], bf0, Cp, 0, 0, 0);
                    Cp = __builtin_amdgcn_mfma_f32_16x16x32_f16(ah1[1], bf1, Cp, 0, 0, 0);
                    if (n16 < 4) {     // M=16: all quads hold valid rows
                        #pragma unroll
                        for (int r = 0; r < 4; ++r)
                            predsS[(quad * 4 + r) * (STEPS * D_IN) + s * D_IN + n16] = Cp[r];
                    }
                }
                #pragma unroll
                for (int r = 0; r < 4; ++r) {
                    const _Float16 h = cell_h(Cacc[0][r], Cacc[1][r], Cacc[2][r], Cacc[3][r], &csv[r]);
                    nxt[(quad * 4 + r) * A1S + jcol] = h;
                }
            } else {   // grp0-halves pre-compute Cacc(s+1) = b1 + Whh1·h1(s), dup
                #pragma unroll
                for (int tau = 0; tau < 4; ++tau)
                    Cacc[tau] = (float4v){bias[tau], bias[tau], bias[tau], bias[tau]};
                #pragma unroll
                for (int kt = 0; kt < 2; ++kt)
                    #pragma unroll
                    for (int tau = 0; tau < 4; ++tau)
                        Cacc[tau] = __builtin_amdgcn_mfma_f32_16x16x32_f16(ah1[kt], Bw[2 + kt][tau], Cacc[tau], 0, 0, 0);
            }
        }
        __syncthreads();   // B2: h0(s+1) visible
    }

    // ---- bulk store preds ----
    for (int j = tid; j < M_BLK * STEPS; j += NTHREADS) {
        const int elem = j / STEPS, r = j - elem * STEPS;
        ((float4v*)out)[(size_t)(m0 + elem) * STEPS + r] = ((const float4v*)predsS)[j];
    }
}

extern "C" void kernel_launch(void* const* d_in, const int* in_sizes, int n_in,
                              void* d_out, int out_size, void* d_ws, size_t ws_size,
                              hipStream_t stream) {
    const float* x    = (const float*)d_in[0];
    const float* Wih0 = (const float*)d_in[1];
    const float* Whh0 = (const float*)d_in[2];
    const float* bih0 = (const float*)d_in[3];
    const float* bhh0 = (const float*)d_in[4];
    const float* Wih1 = (const float*)d_in[5];
    const float* Whh1 = (const float*)d_in[6];
    const float* bih1 = (const float*)d_in[7];
    const float* bhh1 = (const float*)d_in[8];
    const float* Wfc  = (const float*)d_in[9];
    const float* bfc  = (const float*)d_in[10];
    float* out = (float*)d_out;

    dim3 grid(4096 / M_BLK);   // 256 blocks, one per CU
    dim3 block(NTHREADS);      // 12 waves = 3/SIMD: {L1-lo, L1-hi, L0}
    lstm_ar_kernel<<<grid, block, 0, stream>>>(
        x, Wih0, Whh0, bih0, bhh0, Wih1, Whh1, bih1, bhh1, Wfc, bfc, out);
}